// Round 10
// baseline (11210.341 us; speedup 1.0000x reference)
//
#include <hip/hip_runtime.h>
#include <hip/hip_bf16.h>
#include <hip/hip_fp16.h>
#include <stdint.h>

#define LL 4096
#define EE 300
#define HH 512
#define G4H 2048
#define TT 11
#define TSTART 9
#define TSTOP 10
#define NEGINF -10000.0f

typedef unsigned long long u64;
typedef _Float16 h2v __attribute__((ext_vector_type(2)));

__device__ __forceinline__ float sigf(float x){
    x = fminf(fmaxf(x, -30.f), 30.f);
    return 1.0f / (1.0f + __expf(-x));
}
__device__ __forceinline__ float tanhfast(float x){
    x = fminf(fmaxf(x, -15.f), 15.f);
    float e = __expf(-2.0f * x);
    return (1.0f - e) / (1.0f + e);
}
__device__ __forceinline__ u64 lda(const u64* p){
    return __hip_atomic_load(p, __ATOMIC_RELAXED, __HIP_MEMORY_SCOPE_AGENT);
}
__device__ __forceinline__ h2v u2h(unsigned u){
    union { unsigned v; h2v h; } c; c.v = u; return c.h;
}
__device__ __forceinline__ h2v pk(float a, float b){
    auto r = __builtin_amdgcn_cvt_pkrtz(a, b);      // __fp16 ext_vector(2)
    union { decltype(r) x; h2v h; } c; c.x = r; return c.h;
}

// ---------------- K0: zero the h-communication buffers (fresh tags each call)
__global__ void k0_zero(u64* __restrict__ comm){
    int i = blockIdx.x * blockDim.x + threadIdx.x;
    if (i < 2 * 2 * HH) comm[i] = 0ull;
}

// ---------------- K1: xg[dir][t][r] = emb[sent[t]] . w_ih[dir][r] + b_ih[r] + b_hh[r]
__global__ __launch_bounds__(256) void k1_xg(
    const int* __restrict__ sent, const float* __restrict__ emb,
    const float* __restrict__ wih_f, const float* __restrict__ bih_f, const float* __restrict__ bhh_f,
    const float* __restrict__ wih_b, const float* __restrict__ bih_b, const float* __restrict__ bhh_b,
    float* __restrict__ xg_f, float* __restrict__ xg_b)
{
    __shared__ float elds[32 * 304];
    int t0  = blockIdx.x * 32;
    int r0  = blockIdx.y * 256;
    int dir = blockIdx.z;
    const float* wih = dir ? wih_b : wih_f;
    const float* bih = dir ? bih_b : bih_f;
    const float* bhh = dir ? bhh_b : bhh_f;
    float* xg = dir ? xg_b : xg_f;

    for (int idx = threadIdx.x; idx < 32 * EE; idx += 256){
        int i = idx / EE, e = idx - i * EE;
        elds[i * 304 + e] = emb[(long)sent[t0 + i] * EE + e];
    }
    __syncthreads();

    int rA = r0 + (threadIdx.x & 127);
    int rB = rA + 128;
    int half = threadIdx.x >> 7;
    float accA[16], accB[16];
    #pragma unroll
    for (int i = 0; i < 16; i++){ accA[i] = 0.f; accB[i] = 0.f; }
    const float* wrowA = wih + (long)rA * EE;
    const float* wrowB = wih + (long)rB * EE;
    for (int e4 = 0; e4 < 75; e4++){
        float4 wa = *reinterpret_cast<const float4*>(wrowA + e4 * 4);
        float4 wb = *reinterpret_cast<const float4*>(wrowB + e4 * 4);
        #pragma unroll
        for (int i = 0; i < 16; i++){
            float4 ev = *reinterpret_cast<const float4*>(&elds[(half * 16 + i) * 304 + e4 * 4]);
            accA[i] += wa.x * ev.x + wa.y * ev.y + wa.z * ev.z + wa.w * ev.w;
            accB[i] += wb.x * ev.x + wb.y * ev.y + wb.z * ev.z + wb.w * ev.w;
        }
    }
    float bA = bih[rA] + bhh[rA];
    float bB = bih[rB] + bhh[rB];
    #pragma unroll
    for (int i = 0; i < 16; i++){
        int t = t0 + half * 16 + i;
        xg[(long)t * G4H + rA] = accA[i] + bA;
        xg[(long)t * G4H + rB] = accB[i] + bB;
    }
}

// ---------------- K2: persistent BiLSTM — 4-deep pipelined poll + wave-
// autonomous reduce-scatter tail. 64 blocks x 512 thr; bid>>5 = dir, b=bid&31
// owns j [16b,16b+16); wave w owns outputs {16b+2w, 16b+2w+1}.
// Per step: thread tid polls comm word tid with a 4-deep rolling pipeline
// (sample grain ~RT/4), stages f16 to LDS, ONE barrier; each lane reads its
// 8-f16 h slice (one b128, no broadcast), 32 dot2 over 8 rows, 14-shfl
// reduce-scatter butterfly (R5-verified), exec-uniform gates, lanes 0/4 of
// each wave publish. No plds, no second barrier, no wave0 serialization.
__global__ __launch_bounds__(512) void k2_lstm(
    const float* __restrict__ whh_f, const float* __restrict__ whh_b,
    const float* __restrict__ xg_f, const float* __restrict__ xg_b,
    float* __restrict__ hs_f, float* __restrict__ hs_b,
    u64* __restrict__ comm)
{
    int dir = blockIdx.x >> 5;
    int b   = blockIdx.x & 31;
    int j0  = b * 16;
    int tid = threadIdx.x;
    int w   = tid >> 6;
    int l   = tid & 63;
    int jp  = (l >> 2) & 1;
    int jA  = j0 + 2 * w;
    int b0  = l & 1, b1 = (l >> 1) & 1, b2 = jp;

    const float* whh = dir ? whh_b : whh_f;
    const float* xg  = dir ? xg_b  : xg_f;
    float* hs        = dir ? hs_b  : hs_f;
    u64* cm          = comm + dir * 2 * HH;

    // wreg[r][i]: r = jp'*4+g' -> global row (r&3)*HH + jA + (r>>2), cols [8l,8l+8)
    h2v wreg[8][4];
    #pragma unroll
    for (int r = 0; r < 8; r++){
        const float* wp = whh + (size_t)((r & 3) * HH + jA + (r >> 2)) * HH + 8 * l;
        float4 v0 = *reinterpret_cast<const float4*>(wp);
        float4 v1 = *reinterpret_cast<const float4*>(wp + 4);
        wreg[r][0] = pk(v0.x, v0.y);
        wreg[r][1] = pk(v0.z, v0.w);
        wreg[r][2] = pk(v1.x, v1.y);
        wreg[r][3] = pk(v1.z, v1.w);
    }

    __shared__ __align__(16) unsigned short hl16[2][HH];
    float c = 0.f;

    for (int s = 0; s < LL; ++s){
        int t = dir ? (LL - 1 - s) : s;
        // xg for my (gate l&3, output jA+jp); in flight during the poll
        float xgd = xg[(size_t)t * G4H + (l & 3) * HH + jA + jp];

        if (s == 0){
            hl16[0][tid] = 0;
        } else {
            const u64* pw = cm + (s & 1) * HH + tid;
            // 4-deep rolling pipelined poll: issue 1 load/iter, check the one
            // issued 4 iterations ago -> sample grain ~RT/4, staleness ~RT.
            u64 v0 = lda(pw), v1 = lda(pw), v2 = lda(pw), v3 = lda(pw);
            unsigned want = (unsigned)s;
            while (!__all((unsigned)(v0 >> 32) == want)){
                v0 = v1; v1 = v2; v2 = v3; v3 = lda(pw);
            }
            float hval = __uint_as_float((unsigned)v0);
            union { h2v h; unsigned u; } cv2; cv2.h = pk(hval, hval);
            hl16[s & 1][tid] = (unsigned short)(cv2.u & 0xFFFFu);
        }
        __syncthreads();
        // Reuse safety (one barrier/step): hl16[s&1] is overwritten at staging
        // s+2, which needs poll(s+2) success, which needs every local wave's
        // publish(s+2), which (data dep) follows its dot(s+1), which follows
        // barrier(s+1), which follows staging(s+1), which needs poll(s+1),
        // which needs every local publish(s+1), which follows each wave's
        // dot(s) -- and every wave reads ALL of hl16[s&1] in its dot(s).

        // per-lane h slice: cols [8l, 8l+8) as 4 packed f16 pairs (one b128)
        uint4 hv4 = *reinterpret_cast<const uint4*>(&hl16[s & 1][8 * l]);
        h2v h0 = u2h(hv4.x), h1 = u2h(hv4.y), h2 = u2h(hv4.z), h3 = u2h(hv4.w);

        float acc[8];
        #pragma unroll
        for (int r = 0; r < 8; r++){
            float a = __builtin_amdgcn_fdot2(wreg[r][0], h0, 0.f,  false);
            a = __builtin_amdgcn_fdot2(wreg[r][1], h1, a, false);
            a = __builtin_amdgcn_fdot2(wreg[r][2], h2, a, false);
            acc[r] = __builtin_amdgcn_fdot2(wreg[r][3], h3, a, false);
        }

        // reduce-scatter butterfly (R5-verified): end state lane holds row l&7
        float t1[4];
        #pragma unroll
        for (int m = 0; m < 4; m++){
            float tx = b0 ? acc[2 * m]     : acc[2 * m + 1];
            float kp = b0 ? acc[2 * m + 1] : acc[2 * m];
            t1[m] = kp + __shfl_xor(tx, 1, 64);
        }
        float t2[2];
        #pragma unroll
        for (int m = 0; m < 2; m++){
            float tx = b1 ? t1[2 * m]     : t1[2 * m + 1];
            float kp = b1 ? t1[2 * m + 1] : t1[2 * m];
            t2[m] = kp + __shfl_xor(tx, 2, 64);
        }
        float tx3 = b2 ? t2[0] : t2[1];
        float kp3 = b2 ? t2[1] : t2[0];
        float d = kp3 + __shfl_xor(tx3, 4, 64);
        d += __shfl_xor(d, 8, 64);
        d += __shfl_xor(d, 16, 64);
        d += __shfl_xor(d, 32, 64);

        float pre = d + xgd;              // full preact of (gate l&3, output jA+jp)
        int base = l & 60;
        float vi = __shfl(pre, base,     64);
        float vf = __shfl(pre, base + 1, 64);
        float vg = __shfl(pre, base + 2, 64);
        float vo = __shfl(pre, base + 3, 64);
        c = sigf(vf) * c + sigf(vi) * tanhfast(vg);
        float hv = sigf(vo) * tanhfast(c);

        if (l == 0 || l == 4){
            int j = jA + jp;
            union { float f; unsigned u; } cv; cv.f = hv;
            u64 pk2 = ((u64)(s + 1) << 32) | (u64)cv.u;
            __hip_atomic_store(cm + ((s + 1) & 1) * HH + j, pk2,
                               __ATOMIC_RELAXED, __HIP_MEMORY_SCOPE_AGENT);
            hs[(size_t)t * HH + j] = hv;
        }
    }
}

// ---------------- K3: feats[t][n] = w_tag[n] . [hf[t], hb[t]] + b_tag[n]
__global__ __launch_bounds__(64) void k3_feats(
    const float* __restrict__ hs_f, const float* __restrict__ hs_b,
    const float* __restrict__ wtag, const float* __restrict__ btag,
    float* __restrict__ feats)
{
    int t = blockIdx.x;
    int lane = threadIdx.x;
    float hreg[16];
    #pragma unroll
    for (int q = 0; q < 16; q++){
        int k = q * 64 + lane;
        hreg[q] = (q < 8) ? hs_f[(long)t * HH + k] : hs_b[(long)t * HH + (k - HH)];
    }
    for (int n = 0; n < TT; n++){
        float a = 0.f;
        #pragma unroll
        for (int q = 0; q < 16; q++){
            a += wtag[n * 1024 + q * 64 + lane] * hreg[q];
        }
        #pragma unroll
        for (int off = 32; off; off >>= 1) a += __shfl_down(a, off, 64);
        if (lane == 0) feats[t * 12 + n] = a + btag[n];
    }
}

// ---------------- K4a: per-chunk max-plus products P_c[n][s] (64 chunks of 64)
__global__ __launch_bounds__(64) void k4a_chunk(
    const float* __restrict__ feats, const float* __restrict__ trans,
    float* __restrict__ Pmat)
{
    int c = blockIdx.x;
    int lane = threadIdx.x;             // lane = start state s (active < TT)
    float tr[TT][TT];
    #pragma unroll
    for (int n = 0; n < TT; n++)
        #pragma unroll
        for (int p = 0; p < TT; p++) tr[n][p] = trans[n * TT + p];

    float pv[TT];
    #pragma unroll
    for (int n = 0; n < TT; n++) pv[n] = (n == lane) ? 0.f : NEGINF;

    for (int i = 0; i < 64; i++){
        int t = c * 64 + i;
        float ft[TT];
        #pragma unroll
        for (int n = 0; n < TT; n++) ft[n] = feats[t * 12 + n];
        float pn[TT];
        #pragma unroll
        for (int n = 0; n < TT; n++){
            float m = tr[n][0] + pv[0];
            #pragma unroll
            for (int p = 1; p < TT; p++) m = fmaxf(m, tr[n][p] + pv[p]);
            pn[n] = m + ft[n];
        }
        #pragma unroll
        for (int n = 0; n < TT; n++) pv[n] = pn[n];
    }
    if (lane < TT){
        #pragma unroll
        for (int n = 0; n < TT; n++) Pmat[(c * TT + n) * TT + lane] = pv[n];
    }
}

// ---------------- K4b: sequential boundary combine (fv before each chunk)
__global__ __launch_bounds__(64) void k4b_bound(
    const float* __restrict__ Pmat, float* __restrict__ fvb)
{
    int lane = threadIdx.x;
    int ln = (lane < TT) ? lane : 0;
    float fv[TT];
    #pragma unroll
    for (int n = 0; n < TT; n++) fv[n] = (n == TSTART) ? 0.f : NEGINF;

    for (int c = 0; c < 64; c++){
        if (lane < TT) fvb[c * TT + lane] = fv[lane];
        float nf = NEGINF;
        #pragma unroll
        for (int s = 0; s < TT; s++)
            nf = fmaxf(nf, Pmat[(c * TT + ln) * TT + s] + fv[s]);
        #pragma unroll
        for (int n = 0; n < TT; n++) fv[n] = __shfl(nf, n, 64);
    }
    if (lane < TT) fvb[64 * TT + lane] = fv[lane];
}

// ---------------- K4c: per-chunk backpointer recompute (nibble-packed u64/step)
__global__ __launch_bounds__(64) void k4c_bp(
    const float* __restrict__ feats, const float* __restrict__ trans,
    const float* __restrict__ fvb, u64* __restrict__ bpw)
{
    int c = blockIdx.x;
    int lane = threadIdx.x;             // lane = next state n (active < TT)
    int ln = (lane < TT) ? lane : 0;
    float trl[TT];
    #pragma unroll
    for (int p = 0; p < TT; p++) trl[p] = trans[ln * TT + p];
    float fv[TT];
    #pragma unroll
    for (int n = 0; n < TT; n++) fv[n] = fvb[c * TT + n];

    for (int i = 0; i < 64; i++){
        int t = c * 64 + i;
        float best = NEGINF; int bp = 0;
        #pragma unroll
        for (int p = 0; p < TT; p++){
            float sp = trl[p] + fv[p];
            if (sp > best){ best = sp; bp = p; }
        }
        if (lane >= TT) bp = 0;
        unsigned lo = (lane < 8) ? ((unsigned)bp << (4 * lane)) : 0u;
        unsigned hi = (lane >= 8 && lane < TT) ? ((unsigned)bp << (4 * (lane - 8))) : 0u;
        #pragma unroll
        for (int off = 1; off < 16; off <<= 1){
            lo |= __shfl_xor(lo, off, 16); hi |= __shfl_xor(hi, off, 16);
        }
        if (lane == 0) bpw[t] = (u64)lo | ((u64)hi << 32);
        float nf = (lane < TT) ? best + feats[t * 12 + ln] : NEGINF;
        #pragma unroll
        for (int n = 0; n < TT; n++) fv[n] = __shfl(nf, n, 64);
    }
}

// ---------------- K4d: terminal + backtrace
__global__ __launch_bounds__(256) void k4d_bt(
    const u64* __restrict__ bpw, const float* __restrict__ fvb,
    const float* __restrict__ trans, float* __restrict__ out)
{
    __shared__ u64 bl[LL];
    int tid = threadIdx.x;
    for (int i = tid; i < LL; i += 256) bl[i] = bpw[i];
    __syncthreads();

    if (tid < 64){
        int lane = tid;
        int ln = (lane < TT) ? lane : 0;
        float term = (lane < TT) ? (fvb[64 * TT + ln] + trans[TSTOP * TT + ln]) : -3.0e38f;
        int idx = (lane < TT) ? lane : 63;
        #pragma unroll
        for (int off = 32; off; off >>= 1){
            float os = __shfl_down(term, off, 64);
            int   oi = __shfl_down(idx,  off, 64);
            if (os > term || (os == term && oi < idx)){ term = os; idx = oi; }
        }
        if (lane == 0){
            out[0] = term;
            int tag = idx;
            out[1 + (LL - 1)] = (float)tag;
            for (int u = LL - 1; u >= 1; --u){
                tag = (int)((bl[u] >> (4 * tag)) & 15ull);
                out[u] = (float)tag;   // out[1 + (u-1)]
            }
        }
    }
}

__global__ void k_dbg(float* out, float v){ out[0] = v; }

extern "C" void kernel_launch(void* const* d_in, const int* in_sizes, int n_in,
                              void* d_out, int out_size, void* d_ws, size_t ws_size,
                              hipStream_t stream)
{
    const int*   sent  = (const int*)  d_in[0];
    const float* emb   = (const float*)d_in[1];
    const float* wih_f = (const float*)d_in[2];
    const float* whh_f = (const float*)d_in[3];
    const float* bih_f = (const float*)d_in[4];
    const float* bhh_f = (const float*)d_in[5];
    const float* wih_b = (const float*)d_in[6];
    const float* whh_b = (const float*)d_in[7];
    const float* bih_b = (const float*)d_in[8];
    const float* bhh_b = (const float*)d_in[9];
    const float* wtag  = (const float*)d_in[10];
    const float* btag  = (const float*)d_in[11];
    const float* trans = (const float*)d_in[12];
    float* out = (float*)d_out;

    char* ws = (char*)d_ws;
    size_t off = 0;
    float* xg_f = (float*)(ws + off); off += (size_t)LL * G4H * 4;
    float* xg_b = (float*)(ws + off); off += (size_t)LL * G4H * 4;
    float* hs_f = (float*)(ws + off); off += (size_t)LL * HH * 4;
    float* hs_b = (float*)(ws + off); off += (size_t)LL * HH * 4;
    float* feats= (float*)(ws + off); off += (size_t)LL * 12 * 4;
    u64* comm   = (u64*)(ws + off);   off += 2 * 2 * HH * 8;
    float* Pmat = (float*)(ws + off); off += (size_t)64 * TT * TT * 4;
    float* fvb  = (float*)(ws + off); off += (size_t)65 * TT * 4 + 64;
    u64* bpw    = (u64*)(ws + off);   off += (size_t)LL * 8;

    if (off > ws_size){
        k_dbg<<<1, 1, 0, stream>>>(out, (float)ws_size);
        return;
    }

    k0_zero<<<8, 256, 0, stream>>>(comm);
    k1_xg<<<dim3(128, 8, 2), 256, 0, stream>>>(sent, emb, wih_f, bih_f, bhh_f,
                                               wih_b, bih_b, bhh_b, xg_f, xg_b);
    k2_lstm<<<64, 512, 0, stream>>>(whh_f, whh_b, xg_f, xg_b, hs_f, hs_b, comm);
    k3_feats<<<LL, 64, 0, stream>>>(hs_f, hs_b, wtag, btag, feats);
    k4a_chunk<<<64, 64, 0, stream>>>(feats, trans, Pmat);
    k4b_bound<<<1, 64, 0, stream>>>(Pmat, fvb);
    k4c_bp<<<64, 64, 0, stream>>>(feats, trans, fvb, bpw);
    k4d_bt<<<1, 256, 0, stream>>>(bpw, fvb, trans, out);
}

// Round 11
// 6972.752 us; speedup vs baseline: 1.6077x; 1.6077x over previous
//
#include <hip/hip_runtime.h>
#include <hip/hip_bf16.h>
#include <hip/hip_fp16.h>
#include <stdint.h>

#define LL 4096
#define EE 300
#define HH 512
#define G4H 2048
#define TT 11
#define TSTART 9
#define TSTOP 10
#define NEGINF -10000.0f
#define NW 256   // packed comm words per direction per parity

typedef unsigned long long u64;
typedef _Float16 h2v __attribute__((ext_vector_type(2)));

__device__ __forceinline__ float sigf(float x){
    x = fminf(fmaxf(x, -30.f), 30.f);
    return 1.0f / (1.0f + __expf(-x));
}
__device__ __forceinline__ float tanhfast(float x){
    x = fminf(fmaxf(x, -15.f), 15.f);
    float e = __expf(-2.0f * x);
    return (1.0f - e) / (1.0f + e);
}
__device__ __forceinline__ u64 lda(const u64* p){
    return __hip_atomic_load(p, __ATOMIC_RELAXED, __HIP_MEMORY_SCOPE_AGENT);
}
__device__ __forceinline__ h2v u2h(unsigned u){
    union { unsigned v; h2v h; } c; c.v = u; return c.h;
}
__device__ __forceinline__ h2v pk(float a, float b){
    auto r = __builtin_amdgcn_cvt_pkrtz(a, b);      // __fp16 ext_vector(2)
    union { decltype(r) x; h2v h; } c; c.x = r; return c.h;
}
__device__ __forceinline__ unsigned pku(float a, float b){  // packed f16 pair bits
    auto r = __builtin_amdgcn_cvt_pkrtz(a, b);
    union { decltype(r) x; unsigned u; } c; c.x = r; return c.u;
}

// ---------------- K0: zero the h-communication buffers (fresh tags each call)
__global__ void k0_zero(u64* __restrict__ comm){
    int i = blockIdx.x * blockDim.x + threadIdx.x;
    if (i < 2 * 2 * NW) comm[i] = 0ull;
}

// ---------------- K1: xg[dir][t][r] = emb[sent[t]] . w_ih[dir][r] + b_ih[r] + b_hh[r]
__global__ __launch_bounds__(256) void k1_xg(
    const int* __restrict__ sent, const float* __restrict__ emb,
    const float* __restrict__ wih_f, const float* __restrict__ bih_f, const float* __restrict__ bhh_f,
    const float* __restrict__ wih_b, const float* __restrict__ bih_b, const float* __restrict__ bhh_b,
    float* __restrict__ xg_f, float* __restrict__ xg_b)
{
    __shared__ float elds[32 * 304];
    int t0  = blockIdx.x * 32;
    int r0  = blockIdx.y * 256;
    int dir = blockIdx.z;
    const float* wih = dir ? wih_b : wih_f;
    const float* bih = dir ? bih_b : bih_f;
    const float* bhh = dir ? bhh_b : bhh_f;
    float* xg = dir ? xg_b : xg_f;

    for (int idx = threadIdx.x; idx < 32 * EE; idx += 256){
        int i = idx / EE, e = idx - i * EE;
        elds[i * 304 + e] = emb[(long)sent[t0 + i] * EE + e];
    }
    __syncthreads();

    int rA = r0 + (threadIdx.x & 127);
    int rB = rA + 128;
    int half = threadIdx.x >> 7;
    float accA[16], accB[16];
    #pragma unroll
    for (int i = 0; i < 16; i++){ accA[i] = 0.f; accB[i] = 0.f; }
    const float* wrowA = wih + (long)rA * EE;
    const float* wrowB = wih + (long)rB * EE;
    for (int e4 = 0; e4 < 75; e4++){
        float4 wa = *reinterpret_cast<const float4*>(wrowA + e4 * 4);
        float4 wb = *reinterpret_cast<const float4*>(wrowB + e4 * 4);
        #pragma unroll
        for (int i = 0; i < 16; i++){
            float4 ev = *reinterpret_cast<const float4*>(&elds[(half * 16 + i) * 304 + e4 * 4]);
            accA[i] += wa.x * ev.x + wa.y * ev.y + wa.z * ev.z + wa.w * ev.w;
            accB[i] += wb.x * ev.x + wb.y * ev.y + wb.z * ev.z + wb.w * ev.w;
        }
    }
    float bA = bih[rA] + bhh[rA];
    float bB = bih[rB] + bhh[rB];
    #pragma unroll
    for (int i = 0; i < 16; i++){
        int t = t0 + half * 16 + i;
        xg[(long)t * G4H + rA] = accA[i] + bA;
        xg[(long)t * G4H + rB] = accB[i] + bB;
    }
}

// ---------------- K2: persistent BiLSTM — R9 structure + packed comm words +
// depth-2 rolling poll at CONSTANT total issue rate.
// 64 blocks x 512 thr. bid>>5 = dir, b = bid&31 owns j [16b,16b+16).
// Comm word i (i<256/dir/parity) = {tag u32 | f16 h[2i+1] : f16 h[2i]}.
// Per step: threads 0-255 poll word tid with a depth-2 rolling pipeline
// (grain ~RT/2; total issue = R9 baseline since words halved), stage payload
// u32 straight into hl16; ONE barrier; R9 dot (8 b128 wave-uniform reads + 32
// dot2); wave0 tail: plds reduce + gates; even lanes<16 publish packed pairs.
__global__ __launch_bounds__(512) void k2_lstm(
    const float* __restrict__ whh_f, const float* __restrict__ whh_b,
    const float* __restrict__ xg_f, const float* __restrict__ xg_b,
    float* __restrict__ hs_f, float* __restrict__ hs_b,
    u64* __restrict__ comm)
{
    int dir = blockIdx.x >> 5;
    int b   = blockIdx.x & 31;
    int j0  = b * 16;
    int tid = threadIdx.x;
    int w   = tid >> 6;
    int l   = tid & 63;
    int g   = l >> 4;
    int jl  = l & 15;
    int row = g * HH + j0 + jl;

    const float* whh = dir ? whh_b : whh_f;
    const float* xg  = dir ? xg_b  : xg_f;
    float* hs        = dir ? hs_b  : hs_f;
    u64* cm          = comm + dir * 2 * NW;

    // weights for my row, cols [w*64, w*64+64), packed f16 pairs
    h2v wreg[32];
    {
        const float* wp = whh + (size_t)row * HH + w * 64;
        #pragma unroll
        for (int m = 0; m < 32; m += 2){
            float4 v = *reinterpret_cast<const float4*>(wp + 2 * m);
            wreg[m]     = pk(v.x, v.y);
            wreg[m + 1] = pk(v.z, v.w);
        }
    }

    __shared__ __align__(16) unsigned short hl16[2][HH];
    __shared__ float plds[2][512];
    float c = 0.f;

    for (int s = 0; s < LL; ++s){
        int t = dir ? (LL - 1 - s) : s;
        // xg prefetch for the tail (wave0 rows only); in flight during poll
        float xgv = 0.f;
        if (tid < 64) xgv = xg[(size_t)t * G4H + row];

        if (tid < NW){
            unsigned* stage = reinterpret_cast<unsigned*>(&hl16[s & 1][0]);
            if (s == 0){
                stage[tid] = 0u;
            } else {
                const u64* pw = cm + (s & 1) * NW + tid;
                // depth-2 rolling poll: issue 1 load/iter, check the older one.
                // Grain ~RT/2; total issue rate == R9 (half words x 2 depth).
                u64 v0 = lda(pw), v1 = lda(pw);
                unsigned want = (unsigned)s;
                while (!__all((unsigned)(v0 >> 32) == want)){
                    v0 = v1; v1 = lda(pw);
                }
                stage[tid] = (unsigned)v0;    // payload IS the f16 pair
            }
        }
        __syncthreads();
        // Reuse safety (one barrier/step): hl16[s&1] is overwritten at staging
        // s+2, which needs poll(s+2) success, which needs every local wave's
        // publish(s+2), which follows its dot(s+1), which follows barrier(s+1),
        // which follows staging(s+1), which needs poll(s+1), which needs every
        // local publish(s+1), which follows each wave's dot(s) -- and every
        // wave reads ALL of hl16[s&1] in its dot(s).

        // dot over my 64-col slice (wave-uniform broadcast b128 reads)
        float a0 = 0.f, a1 = 0.f, a2 = 0.f, a3 = 0.f;
        {
            const uint4* hseg = reinterpret_cast<const uint4*>(&hl16[s & 1][w * 64]);
            #pragma unroll
            for (int q = 0; q < 8; q += 2){
                uint4 h0 = hseg[q];
                uint4 h1 = hseg[q + 1];
                a0 = __builtin_amdgcn_fdot2(wreg[4*q+0], u2h(h0.x), a0, false);
                a1 = __builtin_amdgcn_fdot2(wreg[4*q+1], u2h(h0.y), a1, false);
                a2 = __builtin_amdgcn_fdot2(wreg[4*q+2], u2h(h0.z), a2, false);
                a3 = __builtin_amdgcn_fdot2(wreg[4*q+3], u2h(h0.w), a3, false);
                a0 = __builtin_amdgcn_fdot2(wreg[4*q+4], u2h(h1.x), a0, false);
                a1 = __builtin_amdgcn_fdot2(wreg[4*q+5], u2h(h1.y), a1, false);
                a2 = __builtin_amdgcn_fdot2(wreg[4*q+6], u2h(h1.z), a2, false);
                a3 = __builtin_amdgcn_fdot2(wreg[4*q+7], u2h(h1.w), a3, false);
            }
        }
        plds[s & 1][tid] = (a0 + a1) + (a2 + a3);
        __syncthreads();

        if (w == 0){
            float sum = 0.f;
            #pragma unroll
            for (int q = 0; q < 8; q++) sum += plds[s & 1][q * 64 + l];
            float pre = sum + xgv;
            float vi = __shfl(pre, jl,      64);
            float vf = __shfl(pre, 16 + jl, 64);
            float vg = __shfl(pre, 32 + jl, 64);
            float vo = __shfl(pre, 48 + jl, 64);
            c = sigf(vf) * c + sigf(vi) * tanhfast(vg);
            float h = sigf(vo) * tanhfast(c);
            // h is replicated across lane groups (lane l tracks j0 + (l&15))
            float hodd = __shfl(h, (l & 15) | 1, 64);   // partner (odd jl)
            if (l < 16){
                if ((l & 1) == 0){
                    unsigned pay = pku(h, hodd);        // low = even j, high = odd j
                    u64 word = ((u64)(s + 1) << 32) | (u64)pay;
                    __hip_atomic_store(cm + ((s + 1) & 1) * NW + (j0 >> 1) + (l >> 1),
                                       word, __ATOMIC_RELAXED, __HIP_MEMORY_SCOPE_AGENT);
                }
                hs[(size_t)t * HH + (j0 + l)] = h;
            }
        }
        // waves 1-7 run ahead to the next poll; plds/hl16 are parity
        // double-buffered, and no wave reaches parity reuse (s+2) before
        // wave0 passes barrier(s+1), which requires it read plds[s&1].
    }
}

// ---------------- K3: feats[t][n] = w_tag[n] . [hf[t], hb[t]] + b_tag[n]
__global__ __launch_bounds__(64) void k3_feats(
    const float* __restrict__ hs_f, const float* __restrict__ hs_b,
    const float* __restrict__ wtag, const float* __restrict__ btag,
    float* __restrict__ feats)
{
    int t = blockIdx.x;
    int lane = threadIdx.x;
    float hreg[16];
    #pragma unroll
    for (int q = 0; q < 16; q++){
        int k = q * 64 + lane;
        hreg[q] = (q < 8) ? hs_f[(long)t * HH + k] : hs_b[(long)t * HH + (k - HH)];
    }
    for (int n = 0; n < TT; n++){
        float a = 0.f;
        #pragma unroll
        for (int q = 0; q < 16; q++){
            a += wtag[n * 1024 + q * 64 + lane] * hreg[q];
        }
        #pragma unroll
        for (int off = 32; off; off >>= 1) a += __shfl_down(a, off, 64);
        if (lane == 0) feats[t * 12 + n] = a + btag[n];
    }
}

// ---------------- K4a: per-chunk max-plus products P_c[n][s] (64 chunks of 64)
__global__ __launch_bounds__(64) void k4a_chunk(
    const float* __restrict__ feats, const float* __restrict__ trans,
    float* __restrict__ Pmat)
{
    int c = blockIdx.x;
    int lane = threadIdx.x;             // lane = start state s (active < TT)
    float tr[TT][TT];
    #pragma unroll
    for (int n = 0; n < TT; n++)
        #pragma unroll
        for (int p = 0; p < TT; p++) tr[n][p] = trans[n * TT + p];

    float pv[TT];
    #pragma unroll
    for (int n = 0; n < TT; n++) pv[n] = (n == lane) ? 0.f : NEGINF;

    for (int i = 0; i < 64; i++){
        int t = c * 64 + i;
        float ft[TT];
        #pragma unroll
        for (int n = 0; n < TT; n++) ft[n] = feats[t * 12 + n];
        float pn[TT];
        #pragma unroll
        for (int n = 0; n < TT; n++){
            float m = tr[n][0] + pv[0];
            #pragma unroll
            for (int p = 1; p < TT; p++) m = fmaxf(m, tr[n][p] + pv[p]);
            pn[n] = m + ft[n];
        }
        #pragma unroll
        for (int n = 0; n < TT; n++) pv[n] = pn[n];
    }
    if (lane < TT){
        #pragma unroll
        for (int n = 0; n < TT; n++) Pmat[(c * TT + n) * TT + lane] = pv[n];
    }
}

// ---------------- K4b: sequential boundary combine (fv before each chunk)
__global__ __launch_bounds__(64) void k4b_bound(
    const float* __restrict__ Pmat, float* __restrict__ fvb)
{
    int lane = threadIdx.x;
    int ln = (lane < TT) ? lane : 0;
    float fv[TT];
    #pragma unroll
    for (int n = 0; n < TT; n++) fv[n] = (n == TSTART) ? 0.f : NEGINF;

    for (int c = 0; c < 64; c++){
        if (lane < TT) fvb[c * TT + lane] = fv[lane];
        float nf = NEGINF;
        #pragma unroll
        for (int s = 0; s < TT; s++)
            nf = fmaxf(nf, Pmat[(c * TT + ln) * TT + s] + fv[s]);
        #pragma unroll
        for (int n = 0; n < TT; n++) fv[n] = __shfl(nf, n, 64);
    }
    if (lane < TT) fvb[64 * TT + lane] = fv[lane];
}

// ---------------- K4c: per-chunk backpointer recompute (nibble-packed u64/step)
__global__ __launch_bounds__(64) void k4c_bp(
    const float* __restrict__ feats, const float* __restrict__ trans,
    const float* __restrict__ fvb, u64* __restrict__ bpw)
{
    int c = blockIdx.x;
    int lane = threadIdx.x;             // lane = next state n (active < TT)
    int ln = (lane < TT) ? lane : 0;
    float trl[TT];
    #pragma unroll
    for (int p = 0; p < TT; p++) trl[p] = trans[ln * TT + p];
    float fv[TT];
    #pragma unroll
    for (int n = 0; n < TT; n++) fv[n] = fvb[c * TT + n];

    for (int i = 0; i < 64; i++){
        int t = c * 64 + i;
        float best = NEGINF; int bp = 0;
        #pragma unroll
        for (int p = 0; p < TT; p++){
            float sp = trl[p] + fv[p];
            if (sp > best){ best = sp; bp = p; }
        }
        if (lane >= TT) bp = 0;
        unsigned lo = (lane < 8) ? ((unsigned)bp << (4 * lane)) : 0u;
        unsigned hi = (lane >= 8 && lane < TT) ? ((unsigned)bp << (4 * (lane - 8))) : 0u;
        #pragma unroll
        for (int off = 1; off < 16; off <<= 1){
            lo |= __shfl_xor(lo, off, 16); hi |= __shfl_xor(hi, off, 16);
        }
        if (lane == 0) bpw[t] = (u64)lo | ((u64)hi << 32);
        float nf = (lane < TT) ? best + feats[t * 12 + ln] : NEGINF;
        #pragma unroll
        for (int n = 0; n < TT; n++) fv[n] = __shfl(nf, n, 64);
    }
}

// ---------------- K4d: terminal + backtrace
__global__ __launch_bounds__(256) void k4d_bt(
    const u64* __restrict__ bpw, const float* __restrict__ fvb,
    const float* __restrict__ trans, float* __restrict__ out)
{
    __shared__ u64 bl[LL];
    int tid = threadIdx.x;
    for (int i = tid; i < LL; i += 256) bl[i] = bpw[i];
    __syncthreads();

    if (tid < 64){
        int lane = tid;
        int ln = (lane < TT) ? lane : 0;
        float term = (lane < TT) ? (fvb[64 * TT + ln] + trans[TSTOP * TT + ln]) : -3.0e38f;
        int idx = (lane < TT) ? lane : 63;
        #pragma unroll
        for (int off = 32; off; off >>= 1){
            float os = __shfl_down(term, off, 64);
            int   oi = __shfl_down(idx,  off, 64);
            if (os > term || (os == term && oi < idx)){ term = os; idx = oi; }
        }
        if (lane == 0){
            out[0] = term;
            int tag = idx;
            out[1 + (LL - 1)] = (float)tag;
            for (int u = LL - 1; u >= 1; --u){
                tag = (int)((bl[u] >> (4 * tag)) & 15ull);
                out[u] = (float)tag;   // out[1 + (u-1)]
            }
        }
    }
}

__global__ void k_dbg(float* out, float v){ out[0] = v; }

extern "C" void kernel_launch(void* const* d_in, const int* in_sizes, int n_in,
                              void* d_out, int out_size, void* d_ws, size_t ws_size,
                              hipStream_t stream)
{
    const int*   sent  = (const int*)  d_in[0];
    const float* emb   = (const float*)d_in[1];
    const float* wih_f = (const float*)d_in[2];
    const float* whh_f = (const float*)d_in[3];
    const float* bih_f = (const float*)d_in[4];
    const float* bhh_f = (const float*)d_in[5];
    const float* wih_b = (const float*)d_in[6];
    const float* whh_b = (const float*)d_in[7];
    const float* bih_b = (const float*)d_in[8];
    const float* bhh_b = (const float*)d_in[9];
    const float* wtag  = (const float*)d_in[10];
    const float* btag  = (const float*)d_in[11];
    const float* trans = (const float*)d_in[12];
    float* out = (float*)d_out;

    char* ws = (char*)d_ws;
    size_t off = 0;
    float* xg_f = (float*)(ws + off); off += (size_t)LL * G4H * 4;
    float* xg_b = (float*)(ws + off); off += (size_t)LL * G4H * 4;
    float* hs_f = (float*)(ws + off); off += (size_t)LL * HH * 4;
    float* hs_b = (float*)(ws + off); off += (size_t)LL * HH * 4;
    float* feats= (float*)(ws + off); off += (size_t)LL * 12 * 4;
    u64* comm   = (u64*)(ws + off);   off += (size_t)2 * 2 * NW * 8;
    float* Pmat = (float*)(ws + off); off += (size_t)64 * TT * TT * 4;
    float* fvb  = (float*)(ws + off); off += (size_t)65 * TT * 4 + 64;
    u64* bpw    = (u64*)(ws + off);   off += (size_t)LL * 8;

    if (off > ws_size){
        k_dbg<<<1, 1, 0, stream>>>(out, (float)ws_size);
        return;
    }

    k0_zero<<<8, 256, 0, stream>>>(comm);
    k1_xg<<<dim3(128, 8, 2), 256, 0, stream>>>(sent, emb, wih_f, bih_f, bhh_f,
                                               wih_b, bih_b, bhh_b, xg_f, xg_b);
    k2_lstm<<<64, 512, 0, stream>>>(whh_f, whh_b, xg_f, xg_b, hs_f, hs_b, comm);
    k3_feats<<<LL, 64, 0, stream>>>(hs_f, hs_b, wtag, btag, feats);
    k4a_chunk<<<64, 64, 0, stream>>>(feats, trans, Pmat);
    k4b_bound<<<1, 64, 0, stream>>>(Pmat, fvb);
    k4c_bp<<<64, 64, 0, stream>>>(feats, trans, fvb, bpw);
    k4d_bt<<<1, 256, 0, stream>>>(bpw, fvb, trans, out);
}